// Round 1
// baseline (93.659 us; speedup 1.0000x reference)
//
#include <hip/hip_runtime.h>

#define BATCH 8
#define NPTS  16384
#define LVOX  605     // 11*11*5
#define ABINS 8
#define CH    23      // 15 dist features + 8 rot features

// ---------------------------------------------------------------------------
// Kernel 1: rotation-voxel histogram.  One block per (a,b) pair (64 blocks).
// LDS-private histogram, LDS atomics, direct write of channels 15..22.
// ---------------------------------------------------------------------------
__global__ __launch_bounds__(256) void rot_hist_kernel(const float* __restrict__ pcd,
                                                       float* __restrict__ out) {
    __shared__ int h[LVOX];
    const int ab = blockIdx.x;
    const int a  = ab >> 3;     // 0..7
    const int b  = ab & 7;      // 0..7
    const int tid = threadIdx.x;

    for (int i = tid; i < LVOX; i += 256) h[i] = 0;
    __syncthreads();

    // cos/sin of ang = pi/8*a - pi/2  (nearest-f32 of the numpy values)
    const float C[8] = { -4.3711388e-08f, 0.3826834323650898f, 0.7071067811865476f,
                         0.9238795325112867f, 1.0f, 0.9238795325112867f,
                         0.7071067811865476f, 0.3826834323650898f };
    const float S[8] = { -1.0f, -0.9238795325112867f, -0.7071067811865476f,
                         -0.3826834323650898f, 0.0f, 0.3826834323650898f,
                         0.7071067811865476f, 0.9238795325112867f };
    const float c = C[a];
    const float s = S[a];

    const float* __restrict__ p = pcd + (size_t)b * NPTS * 3;

    for (int n = tid; n < NPTS; n += 256) {
        const float x = p[n * 3 + 0];
        const float y = p[n * 3 + 1];
        const float z = p[n * 3 + 2];
        // rot = M_a @ p + offset,  offset = (5.5, 5.5, 2.5),  voxel = 1
        const float rx = x * c - y * s + 5.5f;
        const float ry = x * s + y * c + 5.5f;
        const float rz = z + 2.5f;
        const int icx = (int)floorf(rx);
        const int icy = (int)floorf(ry);
        const int icz = (int)floorf(rz);
        const int flat = icz + icy * 5 + icx * 55;
        if (flat >= 0 && flat < LVOX) atomicAdd(&h[flat], 1);
    }
    __syncthreads();

    const float inv_n = 1.0f / (float)NPTS;
    for (int l = tid; l < LVOX; l += 256) {
        out[((size_t)b * LVOX + l) * CH + 15 + a] = (float)h[l] * inv_n;
    }
}

// ---------------------------------------------------------------------------
// Kernel 2: cumulative distance features.  One block per (b,l) pair (4840
// blocks).  Per-thread 15 counters with compile-time thresholds (j+1)^2
// (ceil(sqrt(d2)) <= j  <=>  d2 <= j*j), shuffle-reduced across the block.
// Writes channels 0..14.
// ---------------------------------------------------------------------------
__global__ __launch_bounds__(256) void feature_kernel(const float* __restrict__ pcd,
                                                      float* __restrict__ out) {
    const int bl = blockIdx.x;
    const int b  = bl / LVOX;
    const int l  = bl % LVOX;
    const int gi = l / 55;
    const int gj = (l / 5) % 11;
    const int gk = l % 5;
    const float lx = -5.0f + (float)gi;
    const float ly = -5.0f + (float)gj;
    const float lz = -2.0f + (float)gk;

    const int tid = threadIdx.x;
    const float* __restrict__ p = pcd + (size_t)b * NPTS * 3;

    int cnt[15];
#pragma unroll
    for (int q = 0; q < 15; ++q) cnt[q] = 0;

#pragma unroll 4
    for (int n = tid; n < NPTS; n += 256) {
        const float dx = p[n * 3 + 0] - lx;
        const float dy = p[n * 3 + 1] - ly;
        const float dz = p[n * 3 + 2] - lz;
        const float d2 = fmaf(dx, dx, fmaf(dy, dy, dz * dz));
#pragma unroll
        for (int q = 0; q < 15; ++q) {
            const float thr = (float)((q + 1) * (q + 1));
            cnt[q] += (d2 <= thr) ? 1 : 0;
        }
    }

    // wave (64-lane) shuffle reduction
#pragma unroll
    for (int q = 0; q < 15; ++q) {
#pragma unroll
        for (int off = 32; off > 0; off >>= 1) {
            cnt[q] += __shfl_down(cnt[q], off);
        }
    }

    __shared__ int wsum[4][15];
    const int wid  = tid >> 6;
    const int lane = tid & 63;
    if (lane == 0) {
#pragma unroll
        for (int q = 0; q < 15; ++q) wsum[wid][q] = cnt[q];
    }
    __syncthreads();

    if (tid < 15) {
        const int t = wsum[0][tid] + wsum[1][tid] + wsum[2][tid] + wsum[3][tid];
        out[((size_t)b * LVOX + l) * CH + tid] = (float)t * (1.0f / (float)NPTS);
    }
}

extern "C" void kernel_launch(void* const* d_in, const int* in_sizes, int n_in,
                              void* d_out, int out_size, void* d_ws, size_t ws_size,
                              hipStream_t stream) {
    const float* pcd = (const float*)d_in[0];
    float* out = (float*)d_out;

    hipLaunchKernelGGL(rot_hist_kernel, dim3(ABINS * BATCH), dim3(256), 0, stream,
                       pcd, out);
    hipLaunchKernelGGL(feature_kernel, dim3(BATCH * LVOX), dim3(256), 0, stream,
                       pcd, out);
}